// Round 5
// baseline (686.045 us; speedup 1.0000x reference)
//
#include <hip/hip_runtime.h>
#include <type_traits>
#include <cmath>
#include <cstdint>

#define NRAYS     262144
#define HASHMAP   524288
#define DIM       256
#define NMID      6
#define MBLK      32

typedef __bf16 bf16x8  __attribute__((ext_vector_type(8)));
typedef float  floatx4 __attribute__((ext_vector_type(4)));

// ws layout in __bf16 elements (identical to R1/R4 passing layout):
//   [0, 16384):        W_in  fragments [nc:16][hi/lo][lane:64][j:8]  (K padded 16->32 with zeros)
//   [16384, 802816):   W_mid fragments [L:6][kc:8][nc:16][hi/lo][lane:64][j:8]
#define WIN_ELEMS   16384
#define WL_ELEMS    131072
#define WKC_ELEMS   16384
#define WNC_ELEMS   1024

// Gray-coded XOR swizzle (R4, passing). Conflicts counter proved insensitive —
// keep as-is, do not touch again.
__device__ __forceinline__ int sw_idx(int r, int k) {
  int s = (r ^ (r >> 1)) & 7;
  return (r << 8) + ((((k >> 3) ^ s) << 3) | (k & 7));
}

__global__ __launch_bounds__(256) void prep_weights(
    const float* __restrict__ W_in, const float* __restrict__ W_mid,
    __bf16* __restrict__ wsb)
{
  int tid = blockIdx.x * 256 + threadIdx.x;
  if (tid < 8192) {
    int nc = tid >> 9;
    int pos = tid & 511;           // lane*8 + j
    int lane = pos >> 3, j = pos & 7;
    int k = ((lane >> 4) << 3) + j;          // 0..31
    int n = (nc << 4) + (lane & 15);
    float v = (k < 16) ? W_in[k * DIM + n] : 0.f;
    __bf16 hi = (__bf16)v;
    __bf16 lo = (__bf16)(v - (float)hi);
    wsb[nc * WNC_ELEMS + pos]       = hi;
    wsb[nc * WNC_ELEMS + 512 + pos] = lo;
  } else if (tid < 8192 + 393216) {
    int u = tid - 8192;
    int L    = u >> 16;
    int rem  = u & 65535;
    int kc   = rem >> 13;
    int rem2 = rem & 8191;
    int nc   = rem2 >> 9;
    int pos  = rem2 & 511;
    int lane = pos >> 3, j = pos & 7;
    int k = (kc << 5) + ((lane >> 4) << 3) + j;
    int n = (nc << 4) + (lane & 15);
    float v = W_mid[L * (DIM * DIM) + k * DIM + n];
    __bf16 hi = (__bf16)v;
    __bf16 lo = (__bf16)(v - (float)hi);
    int base = WIN_ELEMS + L * WL_ELEMS + kc * WKC_ELEMS + nc * WNC_ELEMS;
    wsb[base + pos]       = hi;
    wsb[base + 512 + pos] = lo;
  }
}

// MBLK=32: 32 KB LDS/block -> 4-5 independent blocks/CU. The barrier-phased
// layer structure (MFMA phase vs VALU epilogue phase) only fills the MFMA pipe
// when co-resident blocks are anti-phased; 2 blocks/CU (R4) gave 51% MfmaUtil.
// __launch_bounds__ 2nd arg = min waves/EU = blocks/CU for 256-thread blocks.
__global__ __launch_bounds__(256, 4) void mlp_fused(
    const float* __restrict__ x,
    const float* __restrict__ table1,
    const float* __restrict__ table2,
    const __bf16* __restrict__ wsb,
    const float* __restrict__ b_in,
    const float* __restrict__ b_mid,
    const float* __restrict__ W_out,
    const float* __restrict__ b_out,
    float* __restrict__ out,
    int res0, int res1, int res2, int res3)
{
  __shared__ __align__(16) __bf16 hbs[MBLK * 256];   // h split-high, swizzled [ray][k]
  __shared__ __align__(16) __bf16 lbs[MBLK * 256];   // h split-low

  const int tid  = threadIdx.x;
  const int lane = tid & 63;
  const int wave = tid >> 6;
  const int col  = lane & 15;
  const int quad = lane >> 4;
  const int rbase = blockIdx.x * MBLK;

  // ---------------- hash-grid encode: 256 (ray,enc,level) tasks, 1 per thread ----------------
  {
    int r   = tid & 31;
    int el  = tid >> 5;            // 0..7
    int enc = el >> 2, lev = el & 3;
    const float* xp = x + (size_t)(rbase + r) * 4 + enc * 2;
    float px = xp[0], py = xp[1];
    int res = (lev == 0) ? res0 : (lev == 1) ? res1 : (lev == 2) ? res2 : res3;
    float fres = (float)res;
    float xf = px * fres, yf = py * fres;
    float xi = floorf(xf), yi = floorf(yf);
    float fx = xf - xi,  fy = yf - yi;
    uint32_t ix = (uint32_t)xi, iy = (uint32_t)yi;
    const float2* tab = (const float2*)(enc ? table2 : table1) + (size_t)lev * HASHMAP;
    float f0 = 0.f, f1 = 0.f;
    #pragma unroll
    for (int c = 0; c < 4; ++c) {                    // corners (0,0),(0,1),(1,0),(1,1)
      uint32_t c0 = (uint32_t)(c >> 1), c1 = (uint32_t)(c & 1);
      uint32_t h = ((ix + c0) ^ ((iy + c1) * 2654435761u)) & (uint32_t)(HASHMAP - 1);
      float2 v = tab[h];
      float w = (c0 ? fx : 1.f - fx) * (c1 ? fy : 1.f - fy);
      f0 += w * v.x;
      f1 += w * v.y;
    }
    int cb = enc * 8 + lev * 2;                      // emb column (concat: enc-major, level, feat)
    __bf16 h0 = (__bf16)f0;
    hbs[sw_idx(r, cb)] = h0;
    lbs[sw_idx(r, cb)] = (__bf16)(f0 - (float)h0);
    __bf16 h1 = (__bf16)f1;
    hbs[sw_idx(r, cb + 1)] = h1;
    lbs[sw_idx(r, cb + 1)] = (__bf16)(f1 - (float)h1);
  }
  // zero K-pad columns 16..31 for the first (K=32) MFMA: 32*16 = 512 elems
  #pragma unroll
  for (int i = 0; i < 2; ++i) {
    int t = tid + i * 256;
    int r = t >> 4, k = 16 + (t & 15);
    hbs[sw_idx(r, k)] = (__bf16)0.f;
    lbs[sw_idx(r, k)] = (__bf16)0.f;
  }
  __syncthreads();

  floatx4 acc[2][4];

  // One dense layer: D(32x256) = A(32xK) * B(Kx256) with split-bf16 (3 products),
  // then bias + ReLU + re-split back into LDS in A-fragment order for the next layer.
  auto run_layer = [&](auto kc_const, const __bf16* __restrict__ wbase,
                       const float* __restrict__ bias_ptr) {
    constexpr int KCOUNT = decltype(kc_const)::value;
    const floatx4 zv = {0.f, 0.f, 0.f, 0.f};
    #pragma unroll
    for (int mt = 0; mt < 2; ++mt)
      #pragma unroll
      for (int nl = 0; nl < 4; ++nl)
        acc[mt][nl] = zv;

    #pragma unroll
    for (int kc = 0; kc < KCOUNT; ++kc) {
      bf16x8 ah[2], al[2], bh[4], bl[4];
      #pragma unroll
      for (int mt = 0; mt < 2; ++mt) {
        // A-fragment: m = lane&15 (within m-tile), k = kc*32 + quad*8 + j
        int idx = sw_idx(mt * 16 + col, kc * 32 + quad * 8);
        ah[mt] = *(const bf16x8*)&hbs[idx];
        al[mt] = *(const bf16x8*)&lbs[idx];
      }
      #pragma unroll
      for (int nl = 0; nl < 4; ++nl) {
        // B-fragment pre-permuted in ws: one dwordx4 per lane (L2-resident)
        const __bf16* p = wbase + kc * WKC_ELEMS + (wave * 4 + nl) * WNC_ELEMS + lane * 8;
        bh[nl] = *(const bf16x8*)p;
        bl[nl] = *(const bf16x8*)(p + 512);
      }
      #pragma unroll
      for (int nl = 0; nl < 4; ++nl)
        #pragma unroll
        for (int mt = 0; mt < 2; ++mt) {
          acc[mt][nl] = __builtin_amdgcn_mfma_f32_16x16x32_bf16(ah[mt], bh[nl], acc[mt][nl], 0, 0, 0);
          acc[mt][nl] = __builtin_amdgcn_mfma_f32_16x16x32_bf16(ah[mt], bl[nl], acc[mt][nl], 0, 0, 0);
          acc[mt][nl] = __builtin_amdgcn_mfma_f32_16x16x32_bf16(al[mt], bh[nl], acc[mt][nl], 0, 0, 0);
        }
    }
    __syncthreads();   // all waves done reading hbs/lbs before overwrite
    #pragma unroll
    for (int nl = 0; nl < 4; ++nl) {
      int n = wave * 64 + nl * 16 + col;
      float bias = bias_ptr[n];
      #pragma unroll
      for (int mt = 0; mt < 2; ++mt) {
        #pragma unroll
        for (int r = 0; r < 4; ++r) {
          // D layout: col = lane&15, row = quad*4 + r
          int m = mt * 16 + quad * 4 + r;
          float hv = acc[mt][nl][r] + bias;
          hv = fmaxf(hv, 0.f);                 // ReLU is applied pre-matmul next layer
          __bf16 hi = (__bf16)hv;
          int idx = sw_idx(m, n);
          hbs[idx] = hi;
          lbs[idx] = (__bf16)(hv - (float)hi);
        }
      }
    }
    __syncthreads();
  };

  run_layer(std::integral_constant<int, 1>{}, wsb, b_in);
  #pragma clang loop unroll(disable)
  for (int L = 0; L < NMID; ++L)
    run_layer(std::integral_constant<int, 8>{}, wsb + WIN_ELEMS + L * WL_ELEMS, b_mid + L * DIM);

  // ---------------- output layer: out = relu(h) . W_out + b_out (h already relu'd in LDS) ----
  {
    int m = tid >> 3, seg = tid & 7;          // 8 threads per ray, 32 k each
    float sum = 0.f;
    #pragma unroll 4
    for (int i = 0; i < 32; ++i) {
      int k = (seg << 5) + ((i + m) & 31);    // rotate k by m to spread LDS banks
      int idx = sw_idx(m, k);
      float hv = (float)hbs[idx] + (float)lbs[idx];
      sum += hv * W_out[k];
    }
    sum += __shfl_xor(sum, 1);
    sum += __shfl_xor(sum, 2);
    sum += __shfl_xor(sum, 4);
    if (seg == 0) out[rbase + m] = sum + b_out[0];
  }
}

extern "C" void kernel_launch(void* const* d_in, const int* in_sizes, int n_in,
                              void* d_out, int out_size, void* d_ws, size_t ws_size,
                              hipStream_t stream)
{
  const float* x      = (const float*)d_in[0];
  const float* table1 = (const float*)d_in[1];
  const float* table2 = (const float*)d_in[2];
  const float* W_in   = (const float*)d_in[3];
  const float* b_in   = (const float*)d_in[4];
  const float* W_mid  = (const float*)d_in[5];
  const float* b_mid  = (const float*)d_in[6];
  const float* W_out  = (const float*)d_in[7];
  const float* b_out  = (const float*)d_in[8];
  float* out  = (float*)d_out;
  __bf16* wsb = (__bf16*)d_ws;

  // Resolutions: identical double-precision op sequence as the Python module (same libm).
  double b = exp((log(512.0) - log(16.0)) / 3.0);
  int res[4];
  for (int l = 0; l < 4; ++l) res[l] = (int)floor(16.0 * pow(b, (double)l));

  int prep_total = 8192 + 393216;
  prep_weights<<<(prep_total + 255) / 256, 256, 0, stream>>>(W_in, W_mid, wsb);
  mlp_fused<<<NRAYS / MBLK, 256, 0, stream>>>(x, table1, table2, wsb, b_in, b_mid,
                                              W_out, b_out, out,
                                              res[0], res[1], res[2], res[3]);
}

// Round 6
// 456.830 us; speedup vs baseline: 1.5018x; 1.5018x over previous
//
#include <hip/hip_runtime.h>
#include <type_traits>
#include <cmath>
#include <cstdint>

#define NRAYS     262144
#define HASHMAP   524288
#define DIM       256
#define NMID      6
#define MBLK      64

typedef __bf16 bf16x8  __attribute__((ext_vector_type(8)));
typedef float  floatx4 __attribute__((ext_vector_type(4)));

// R6 ws layout (bf16 elements) — weights stored as SINGLE bf16 (hi only):
//   [0, 8192):        W_in  fragments [nc:16][lane:64][j:8]  (K padded 16->32 with zeros)
//   [8192, 401408):   W_mid fragments [L:6][kc:8][nc:16][lane:64][j:8]
// Split-bf16 is retained on ACTIVATIONS only (hh+hl): D = Wb*hh + Wb*hl.
// Dropping the W-lo product costs ~1.1e-3 rel/layer (rms), ~1-2e-7 abs on output.
#define WIN_ELEMS   8192
#define WL_ELEMS    65536
#define WKC_ELEMS   8192
#define WNC_ELEMS   512

// Gray-coded XOR swizzle (R4, passing). Conflict counter proved insensitive to
// swizzle choice (R4 post-mortem) — frozen.
__device__ __forceinline__ int sw_idx(int r, int k) {
  int s = (r ^ (r >> 1)) & 7;
  return (r << 8) + ((((k >> 3) ^ s) << 3) | (k & 7));
}

__global__ __launch_bounds__(256) void prep_weights(
    const float* __restrict__ W_in, const float* __restrict__ W_mid,
    __bf16* __restrict__ wsb)
{
  int tid = blockIdx.x * 256 + threadIdx.x;
  int pos = tid & 511;             // lane*8 + j
  int lane = pos >> 3, j = pos & 7;
  int kk = ((lane >> 4) << 3) + j; // quad*8 + j, 0..31
  if (tid < WIN_ELEMS) {
    int nc = tid >> 9;
    int n = (nc << 4) + (lane & 15);
    float v = (kk < 16) ? W_in[kk * DIM + n] : 0.f;
    wsb[nc * WNC_ELEMS + pos] = (__bf16)v;
  } else if (tid < WIN_ELEMS + 6 * WL_ELEMS) {
    int u = tid - WIN_ELEMS;
    int fid = u >> 9;              // 0..767
    int L   = fid >> 7;
    int rem = fid & 127;
    int kc  = rem >> 4;
    int nc  = rem & 15;
    int k = (kc << 5) + kk;
    int n = (nc << 4) + (lane & 15);
    float v = W_mid[L * (DIM * DIM) + k * DIM + n];
    wsb[WIN_ELEMS + L * WL_ELEMS + kc * WKC_ELEMS + nc * WNC_ELEMS + pos] = (__bf16)v;
  }
}

__global__ __launch_bounds__(256, 2) void mlp_fused(
    const float* __restrict__ x,
    const float* __restrict__ table1,
    const float* __restrict__ table2,
    const __bf16* __restrict__ wsb,
    const float* __restrict__ b_in,
    const float* __restrict__ b_mid,
    const float* __restrict__ W_out,
    const float* __restrict__ b_out,
    float* __restrict__ out,
    int res0, int res1, int res2, int res3)
{
  __shared__ __align__(16) __bf16 hbs[MBLK * 256];   // h split-high, swizzled [ray][k]
  __shared__ __align__(16) __bf16 lbs[MBLK * 256];   // h split-low

  const int tid  = threadIdx.x;
  const int lane = tid & 63;
  const int wave = tid >> 6;
  const int col  = lane & 15;
  const int quad = lane >> 4;
  const int rbase = blockIdx.x * MBLK;

  // ---------------- hash-grid encode: 512 (ray,enc,level) tasks, 2 per thread ----------------
  #pragma unroll
  for (int i = 0; i < 2; ++i) {
    int task = tid + (i << 8);
    int r   = task & 63;
    int el  = task >> 6;           // 0..7
    int enc = el >> 2, lev = el & 3;
    const float* xp = x + (size_t)(rbase + r) * 4 + enc * 2;
    float px = xp[0], py = xp[1];
    int res = (lev == 0) ? res0 : (lev == 1) ? res1 : (lev == 2) ? res2 : res3;
    float fres = (float)res;
    float xf = px * fres, yf = py * fres;
    float xi = floorf(xf), yi = floorf(yf);
    float fx = xf - xi,  fy = yf - yi;
    uint32_t ix = (uint32_t)xi, iy = (uint32_t)yi;
    const float2* tab = (const float2*)(enc ? table2 : table1) + (size_t)lev * HASHMAP;
    float f0 = 0.f, f1 = 0.f;
    #pragma unroll
    for (int c = 0; c < 4; ++c) {                    // corners (0,0),(0,1),(1,0),(1,1)
      uint32_t c0 = (uint32_t)(c >> 1), c1 = (uint32_t)(c & 1);
      uint32_t h = ((ix + c0) ^ ((iy + c1) * 2654435761u)) & (uint32_t)(HASHMAP - 1);
      float2 v = tab[h];
      float w = (c0 ? fx : 1.f - fx) * (c1 ? fy : 1.f - fy);
      f0 += w * v.x;
      f1 += w * v.y;
    }
    int cb = enc * 8 + lev * 2;                      // emb column (concat: enc-major, level, feat)
    __bf16 h0 = (__bf16)f0;
    hbs[sw_idx(r, cb)] = h0;
    lbs[sw_idx(r, cb)] = (__bf16)(f0 - (float)h0);
    __bf16 h1 = (__bf16)f1;
    hbs[sw_idx(r, cb + 1)] = h1;
    lbs[sw_idx(r, cb + 1)] = (__bf16)(f1 - (float)h1);
  }
  // zero K-pad columns 16..31 for the first (K=32) MFMA
  for (int i = tid; i < MBLK * 16; i += 256) {
    int r = i >> 4, k = 16 + (i & 15);
    hbs[sw_idx(r, k)] = (__bf16)0.f;
    lbs[sw_idx(r, k)] = (__bf16)0.f;
  }
  __syncthreads();

  floatx4 acc[4][4];

  // One dense layer: D(64x256) = A(64xK) * B(Kx256); A = h (split hh+hl from LDS),
  // B = bf16 weights (single product each, pre-permuted fragments from L2).
  // Explicit 1-deep B prefetch hides L2 latency at 2 waves/SIMD.
  auto run_layer = [&](auto kc_const, const __bf16* __restrict__ wbase,
                       const float* __restrict__ bias_ptr) {
    constexpr int KCOUNT = decltype(kc_const)::value;
    const floatx4 zv = {0.f, 0.f, 0.f, 0.f};
    #pragma unroll
    for (int mt = 0; mt < 4; ++mt)
      #pragma unroll
      for (int nl = 0; nl < 4; ++nl)
        acc[mt][nl] = zv;

    const __bf16* wlane = wbase + wave * 4 * WNC_ELEMS + lane * 8;
    bf16x8 bcur[4], bnxt[4];
    #pragma unroll
    for (int nl = 0; nl < 4; ++nl)
      bcur[nl] = *(const bf16x8*)(wlane + nl * WNC_ELEMS);

    #pragma unroll
    for (int kc = 0; kc < KCOUNT; ++kc) {
      if (kc + 1 < KCOUNT) {
        const __bf16* wn = wlane + (kc + 1) * WKC_ELEMS;
        #pragma unroll
        for (int nl = 0; nl < 4; ++nl)
          bnxt[nl] = *(const bf16x8*)(wn + nl * WNC_ELEMS);
      }
      bf16x8 ah[4], al[4];
      #pragma unroll
      for (int mt = 0; mt < 4; ++mt) {
        // A-fragment: m = lane&15 (within m-tile), k = kc*32 + quad*8 + j
        int idx = sw_idx(mt * 16 + col, kc * 32 + quad * 8);
        ah[mt] = *(const bf16x8*)&hbs[idx];
        al[mt] = *(const bf16x8*)&lbs[idx];
      }
      // Two passes: 16 independent chains between same-acc RAW pairs.
      #pragma unroll
      for (int nl = 0; nl < 4; ++nl)
        #pragma unroll
        for (int mt = 0; mt < 4; ++mt)
          acc[mt][nl] = __builtin_amdgcn_mfma_f32_16x16x32_bf16(ah[mt], bcur[nl], acc[mt][nl], 0, 0, 0);
      #pragma unroll
      for (int nl = 0; nl < 4; ++nl)
        #pragma unroll
        for (int mt = 0; mt < 4; ++mt)
          acc[mt][nl] = __builtin_amdgcn_mfma_f32_16x16x32_bf16(al[mt], bcur[nl], acc[mt][nl], 0, 0, 0);
      if (kc + 1 < KCOUNT) {
        #pragma unroll
        for (int nl = 0; nl < 4; ++nl)
          bcur[nl] = bnxt[nl];
      }
    }
    __syncthreads();   // all waves done reading hbs/lbs before overwrite
    #pragma unroll
    for (int nl = 0; nl < 4; ++nl) {
      int n = wave * 64 + nl * 16 + col;
      float bias = bias_ptr[n];
      #pragma unroll
      for (int mt = 0; mt < 4; ++mt) {
        #pragma unroll
        for (int r = 0; r < 4; ++r) {
          // D layout: col = lane&15, row = quad*4 + r
          int m = mt * 16 + quad * 4 + r;
          float hv = acc[mt][nl][r] + bias;
          hv = fmaxf(hv, 0.f);                 // ReLU applied pre-matmul next layer
          __bf16 hi = (__bf16)hv;
          int idx = sw_idx(m, n);
          hbs[idx] = hi;
          lbs[idx] = (__bf16)(hv - (float)hi);
        }
      }
    }
    __syncthreads();
  };

  run_layer(std::integral_constant<int, 1>{}, wsb, b_in);
  #pragma clang loop unroll(disable)
  for (int L = 0; L < NMID; ++L)
    run_layer(std::integral_constant<int, 8>{}, wsb + WIN_ELEMS + L * WL_ELEMS, b_mid + L * DIM);

  // ---------------- output layer: out = relu(h) . W_out + b_out (h already relu'd in LDS) ----
  {
    int m = tid >> 2, seg = tid & 3;          // same-m threads adjacent -> shuffle reduce
    float sum = 0.f;
    #pragma unroll 4
    for (int i = 0; i < 64; ++i) {
      int k = (seg << 6) + ((i + m) & 63);    // rotate k by m to spread LDS banks
      int idx = sw_idx(m, k);
      float hv = (float)hbs[idx] + (float)lbs[idx];
      sum += hv * W_out[k];
    }
    sum += __shfl_xor(sum, 1);
    sum += __shfl_xor(sum, 2);
    if (seg == 0) out[rbase + m] = sum + b_out[0];
  }
}

extern "C" void kernel_launch(void* const* d_in, const int* in_sizes, int n_in,
                              void* d_out, int out_size, void* d_ws, size_t ws_size,
                              hipStream_t stream)
{
  const float* x      = (const float*)d_in[0];
  const float* table1 = (const float*)d_in[1];
  const float* table2 = (const float*)d_in[2];
  const float* W_in   = (const float*)d_in[3];
  const float* b_in   = (const float*)d_in[4];
  const float* W_mid  = (const float*)d_in[5];
  const float* b_mid  = (const float*)d_in[6];
  const float* W_out  = (const float*)d_in[7];
  const float* b_out  = (const float*)d_in[8];
  float* out  = (float*)d_out;
  __bf16* wsb = (__bf16*)d_ws;

  // Resolutions: identical double-precision op sequence as the Python module (same libm).
  double b = exp((log(512.0) - log(16.0)) / 3.0);
  int res[4];
  for (int l = 0; l < 4; ++l) res[l] = (int)floor(16.0 * pow(b, (double)l));

  int prep_total = WIN_ELEMS + 6 * WL_ELEMS;   // 401408 = 1568 * 256
  prep_weights<<<prep_total / 256, 256, 0, stream>>>(W_in, W_mid, wsb);
  mlp_fused<<<NRAYS / MBLK, 256, 0, stream>>>(x, table1, table2, wsb, b_in, b_mid,
                                              W_out, b_out, out,
                                              res[0], res[1], res[2], res[3]);
}